// Round 1
// baseline (494.136 us; speedup 1.0000x reference)
//
#include <hip/hip_runtime.h>

#define N_NODES 100000
#define N_EDGES 1600000
#define D_IN 128
#define D_OUT 64

// ws layout: [0, N) dinv (deg during build), [N, N + N*64) hs = (X@W) * dinv[row]

__global__ __launch_bounds__(256) void k_deg_init(float* __restrict__ deg) {
    int i = blockIdx.x * 256 + threadIdx.x;
    if (i < N_NODES) deg[i] = 1.0f;  // self-loop contribution
}

__global__ __launch_bounds__(256) void k_deg_count(const int* __restrict__ dst,
                                                   float* __restrict__ deg) {
    int e = blockIdx.x * 256 + threadIdx.x;
    if (e < N_EDGES) atomicAdd(&deg[dst[e]], 1.0f);
}

__global__ __launch_bounds__(256) void k_dinv(float* __restrict__ deg) {
    int i = blockIdx.x * 256 + threadIdx.x;
    if (i < N_NODES) deg[i] = rsqrtf(deg[i]);  // deg >= 1 always (self-loops)
}

// GEMM: 16 rows/block (4 rows per wave), lane = output column.
// Writes hs = h * dinv[row] and seeds out with self-loop term hs * dinv[row].
__global__ __launch_bounds__(256) void k_gemm(const float* __restrict__ x,
                                              const float* __restrict__ w,
                                              const float* __restrict__ dinv,
                                              float* __restrict__ hs,
                                              float* __restrict__ out) {
    __shared__ float wl[D_IN * D_OUT];  // 32 KB
    __shared__ float xl[16][D_IN];      // 8 KB
    const int t = threadIdx.x;
    for (int i = t; i < D_IN * D_OUT; i += 256) wl[i] = w[i];
    const int row0 = blockIdx.x * 16;  // N_NODES % 16 == 0 -> no tail
    const float4* xg = (const float4*)(x + (size_t)row0 * D_IN);  // 512 float4
    float4* xs = (float4*)&xl[0][0];
    xs[t]       = xg[t];
    xs[t + 256] = xg[t + 256];
    __syncthreads();

    const int wave = t >> 6, lane = t & 63;
    const int r0 = wave * 4;
    float acc0 = 0.f, acc1 = 0.f, acc2 = 0.f, acc3 = 0.f;
#pragma unroll
    for (int k0 = 0; k0 < D_IN; k0 += 4) {
        float4 x0 = *(const float4*)&xl[r0 + 0][k0];
        float4 x1 = *(const float4*)&xl[r0 + 1][k0];
        float4 x2 = *(const float4*)&xl[r0 + 2][k0];
        float4 x3 = *(const float4*)&xl[r0 + 3][k0];
        float w0 = wl[(k0 + 0) * 64 + lane];
        float w1 = wl[(k0 + 1) * 64 + lane];
        float w2 = wl[(k0 + 2) * 64 + lane];
        float w3 = wl[(k0 + 3) * 64 + lane];
        acc0 = fmaf(x0.w, w3, fmaf(x0.z, w2, fmaf(x0.y, w1, fmaf(x0.x, w0, acc0))));
        acc1 = fmaf(x1.w, w3, fmaf(x1.z, w2, fmaf(x1.y, w1, fmaf(x1.x, w0, acc1))));
        acc2 = fmaf(x2.w, w3, fmaf(x2.z, w2, fmaf(x2.y, w1, fmaf(x2.x, w0, acc2))));
        acc3 = fmaf(x3.w, w3, fmaf(x3.z, w2, fmaf(x3.y, w1, fmaf(x3.x, w0, acc3))));
    }
    const int gr = row0 + r0;
    float dv0 = dinv[gr + 0], dv1 = dinv[gr + 1], dv2 = dinv[gr + 2], dv3 = dinv[gr + 3];
    float h0 = acc0 * dv0, h1 = acc1 * dv1, h2 = acc2 * dv2, h3 = acc3 * dv3;
    hs[(size_t)(gr + 0) * 64 + lane] = h0;
    hs[(size_t)(gr + 1) * 64 + lane] = h1;
    hs[(size_t)(gr + 2) * 64 + lane] = h2;
    hs[(size_t)(gr + 3) * 64 + lane] = h3;
    out[(size_t)(gr + 0) * 64 + lane] = h0 * dv0;
    out[(size_t)(gr + 1) * 64 + lane] = h1 * dv1;
    out[(size_t)(gr + 2) * 64 + lane] = h2 * dv2;
    out[(size_t)(gr + 3) * 64 + lane] = h3 * dv3;
}

// One wave per edge: lane j handles output column j.
__global__ __launch_bounds__(256) void k_scatter(const int* __restrict__ src,
                                                 const int* __restrict__ dst,
                                                 const float* __restrict__ dinv,
                                                 const float* __restrict__ hs,
                                                 float* __restrict__ out) {
    int t = blockIdx.x * 256 + threadIdx.x;  // < 102.4M, fits int
    int e = t >> 6, j = t & 63;
    if (e < N_EDGES) {
        int s = src[e], d = dst[e];
        float v = hs[(size_t)s * 64 + j] * dinv[d];
        atomicAdd(&out[(size_t)d * 64 + j], v);
    }
}

__global__ __launch_bounds__(256) void k_finish(float4* __restrict__ out,
                                                const float* __restrict__ bias) {
    int i = blockIdx.x * 256 + threadIdx.x;  // N*64/4 = 1.6M
    if (i < N_NODES * D_OUT / 4) {
        float4 v = out[i];
        int jb = (i & 15) * 4;
        v.x += bias[jb + 0];
        v.y += bias[jb + 1];
        v.z += bias[jb + 2];
        v.w += bias[jb + 3];
        v.x = v.x > 0.f ? v.x : 0.f;
        v.y = v.y > 0.f ? v.y : 0.f;
        v.z = v.z > 0.f ? v.z : 0.f;
        v.w = v.w > 0.f ? v.w : 0.f;
        out[i] = v;
    }
}

extern "C" void kernel_launch(void* const* d_in, const int* in_sizes, int n_in,
                              void* d_out, int out_size, void* d_ws, size_t ws_size,
                              hipStream_t stream) {
    const float* x    = (const float*)d_in[0];
    const int*   ei   = (const int*)d_in[1];   // [2][E] row-major
    const float* w    = (const float*)d_in[2];
    const float* bias = (const float*)d_in[3];
    float* out = (float*)d_out;

    float* ws   = (float*)d_ws;
    float* dinv = ws;              // N floats (deg during build)
    float* hs   = ws + N_NODES;    // N*64 floats

    const int* srcI = ei;
    const int* dstI = ei + N_EDGES;

    hipLaunchKernelGGL(k_deg_init, dim3((N_NODES + 255) / 256), dim3(256), 0, stream, dinv);
    hipLaunchKernelGGL(k_deg_count, dim3((N_EDGES + 255) / 256), dim3(256), 0, stream, dstI, dinv);
    hipLaunchKernelGGL(k_dinv, dim3((N_NODES + 255) / 256), dim3(256), 0, stream, dinv);
    hipLaunchKernelGGL(k_gemm, dim3(N_NODES / 16), dim3(256), 0, stream, x, w, dinv, hs, out);
    hipLaunchKernelGGL(k_scatter, dim3((N_EDGES * 64) / 256), dim3(256), 0, stream,
                       srcI, dstI, dinv, hs, out);
    hipLaunchKernelGGL(k_finish, dim3(N_NODES * D_OUT / 4 / 256), dim3(256), 0, stream,
                       (float4*)out, bias);
}

// Round 2
// 357.380 us; speedup vs baseline: 1.3827x; 1.3827x over previous
//
#include <hip/hip_runtime.h>

#define N_NODES 100000
#define N_EDGES 1600000
#define D_IN 128
#define D_OUT 64
#define SCAN_BLOCKS 98  // ceil(100000 / 1024)

// ws layout (floats/ints, 4B units):
//   dinv       : float[N]
//   hs         : float[N*64]   (X@W) * dinv[row]
//   counts     : int[N]
//   offsets    : int[N]
//   cursor     : int[N]
//   sorted_src : int[E]
//   bsum       : int[SCAN_BLOCKS]

__global__ __launch_bounds__(256) void k_hist(const int* __restrict__ dst,
                                              int* __restrict__ counts) {
    int e = blockIdx.x * 256 + threadIdx.x;
    if (e < N_EDGES) atomicAdd(&counts[dst[e]], 1);
}

// Per-block exclusive scan over 1024 counts (4/thread), emit block sums.
__global__ __launch_bounds__(256) void k_scan1(const int* __restrict__ counts,
                                               int* __restrict__ offsets,
                                               int* __restrict__ bsum) {
    const int t = threadIdx.x, b = blockIdx.x;
    const int i0 = b * 1024 + t * 4;
    int c0 = (i0 + 0 < N_NODES) ? counts[i0 + 0] : 0;
    int c1 = (i0 + 1 < N_NODES) ? counts[i0 + 1] : 0;
    int c2 = (i0 + 2 < N_NODES) ? counts[i0 + 2] : 0;
    int c3 = (i0 + 3 < N_NODES) ? counts[i0 + 3] : 0;
    int tsum = c0 + c1 + c2 + c3;
    int lane = t & 63, wv = t >> 6;
    int v = tsum;
#pragma unroll
    for (int d = 1; d < 64; d <<= 1) {
        int u = __shfl_up(v, d);
        if (lane >= d) v += u;
    }
    __shared__ int wsum[4];
    if (lane == 63) wsum[wv] = v;
    __syncthreads();
    int woff = 0;
#pragma unroll
    for (int k = 0; k < 4; k++) woff += (k < wv) ? wsum[k] : 0;
    int excl = woff + v - tsum;
    if (i0 + 0 < N_NODES) offsets[i0 + 0] = excl;
    if (i0 + 1 < N_NODES) offsets[i0 + 1] = excl + c0;
    if (i0 + 2 < N_NODES) offsets[i0 + 2] = excl + c0 + c1;
    if (i0 + 3 < N_NODES) offsets[i0 + 3] = excl + c0 + c1 + c2;
    if (t == 255) bsum[b] = woff + v;
}

// Exclusive scan of SCAN_BLOCKS block sums (one block).
__global__ __launch_bounds__(128) void k_scan2(int* __restrict__ bsum) {
    __shared__ int s[128];
    int t = threadIdx.x;
    int v = (t < SCAN_BLOCKS) ? bsum[t] : 0;
    s[t] = v;
    __syncthreads();
#pragma unroll
    for (int d = 1; d < 128; d <<= 1) {
        int u = (t >= d) ? s[t - d] : 0;
        __syncthreads();
        s[t] += u;
        __syncthreads();
    }
    if (t < SCAN_BLOCKS) bsum[t] = s[t] - v;  // exclusive
}

// Add block offsets; produce offsets + cursor copy + dinv.
__global__ __launch_bounds__(256) void k_scan3(const int* __restrict__ counts,
                                               int* __restrict__ offsets,
                                               int* __restrict__ cursor,
                                               float* __restrict__ dinv,
                                               const int* __restrict__ bsum) {
    const int t = threadIdx.x, b = blockIdx.x;
    const int boff = bsum[b];
    const int i0 = b * 1024 + t * 4;
#pragma unroll
    for (int k = 0; k < 4; k++) {
        int i = i0 + k;
        if (i < N_NODES) {
            int off = offsets[i] + boff;
            offsets[i] = off;
            cursor[i] = off;
            dinv[i] = rsqrtf((float)counts[i] + 1.0f);
        }
    }
}

__global__ __launch_bounds__(256) void k_fill(const int* __restrict__ src,
                                              const int* __restrict__ dst,
                                              int* __restrict__ cursor,
                                              int* __restrict__ sorted_src) {
    int e = blockIdx.x * 256 + threadIdx.x;
    if (e < N_EDGES) {
        int d = dst[e];
        int pos = atomicAdd(&cursor[d], 1);
        sorted_src[pos] = src[e];
    }
}

// GEMM: 16 rows/block (4 rows per wave), lane = output column.
// Writes hs = (x@w) * dinv[row].
__global__ __launch_bounds__(256) void k_gemm(const float* __restrict__ x,
                                              const float* __restrict__ w,
                                              const float* __restrict__ dinv,
                                              float* __restrict__ hs) {
    __shared__ float wl[D_IN * D_OUT];  // 32 KB
    __shared__ float xl[16][D_IN];      // 8 KB
    const int t = threadIdx.x;
    for (int i = t; i < D_IN * D_OUT; i += 256) wl[i] = w[i];
    const int row0 = blockIdx.x * 16;  // N_NODES % 16 == 0
    const float4* xg = (const float4*)(x + (size_t)row0 * D_IN);
    float4* xs = (float4*)&xl[0][0];
    xs[t]       = xg[t];
    xs[t + 256] = xg[t + 256];
    __syncthreads();

    const int wave = t >> 6, lane = t & 63;
    const int r0 = wave * 4;
    float acc0 = 0.f, acc1 = 0.f, acc2 = 0.f, acc3 = 0.f;
#pragma unroll
    for (int k0 = 0; k0 < D_IN; k0 += 4) {
        float4 x0 = *(const float4*)&xl[r0 + 0][k0];
        float4 x1 = *(const float4*)&xl[r0 + 1][k0];
        float4 x2 = *(const float4*)&xl[r0 + 2][k0];
        float4 x3 = *(const float4*)&xl[r0 + 3][k0];
        float w0 = wl[(k0 + 0) * 64 + lane];
        float w1 = wl[(k0 + 1) * 64 + lane];
        float w2 = wl[(k0 + 2) * 64 + lane];
        float w3 = wl[(k0 + 3) * 64 + lane];
        acc0 = fmaf(x0.w, w3, fmaf(x0.z, w2, fmaf(x0.y, w1, fmaf(x0.x, w0, acc0))));
        acc1 = fmaf(x1.w, w3, fmaf(x1.z, w2, fmaf(x1.y, w1, fmaf(x1.x, w0, acc1))));
        acc2 = fmaf(x2.w, w3, fmaf(x2.z, w2, fmaf(x2.y, w1, fmaf(x2.x, w0, acc2))));
        acc3 = fmaf(x3.w, w3, fmaf(x3.z, w2, fmaf(x3.y, w1, fmaf(x3.x, w0, acc3))));
    }
    const int gr = row0 + r0;
    hs[(size_t)(gr + 0) * 64 + lane] = acc0 * dinv[gr + 0];
    hs[(size_t)(gr + 1) * 64 + lane] = acc1 * dinv[gr + 1];
    hs[(size_t)(gr + 2) * 64 + lane] = acc2 * dinv[gr + 2];
    hs[(size_t)(gr + 3) * 64 + lane] = acc3 * dinv[gr + 3];
}

// One wave per node: lane j = output column j. Gather-sum hs rows of in-edges,
// then out = relu((sum + self) * dinv + bias).
__global__ __launch_bounds__(256) void k_agg(const int* __restrict__ offsets,
                                             const int* __restrict__ counts,
                                             const int* __restrict__ sorted_src,
                                             const float* __restrict__ dinv,
                                             const float* __restrict__ hs,
                                             const float* __restrict__ bias,
                                             float* __restrict__ out) {
    int t = blockIdx.x * 256 + threadIdx.x;
    int node = t >> 6, lane = t & 63;
    if (node >= N_NODES) return;
    int beg = offsets[node];
    int cnt = counts[node];
    float acc = hs[(size_t)node * 64 + lane];  // self-loop term
    for (int base = 0; base < cnt; base += 64) {
        int m = min(64, cnt - base);
        int sl = (base + lane < cnt) ? sorted_src[beg + base + lane] : 0;
#pragma unroll 4
        for (int k = 0; k < m; k++) {
            int s = __shfl(sl, k);
            acc += hs[(size_t)s * 64 + lane];
        }
    }
    float v = acc * dinv[node] + bias[lane];
    out[(size_t)node * 64 + lane] = v > 0.f ? v : 0.f;
}

extern "C" void kernel_launch(void* const* d_in, const int* in_sizes, int n_in,
                              void* d_out, int out_size, void* d_ws, size_t ws_size,
                              hipStream_t stream) {
    const float* x    = (const float*)d_in[0];
    const int*   ei   = (const int*)d_in[1];   // [2][E] row-major
    const float* w    = (const float*)d_in[2];
    const float* bias = (const float*)d_in[3];
    float* out = (float*)d_out;

    float* dinv       = (float*)d_ws;                 // N
    float* hs         = dinv + N_NODES;               // N*64
    int*   counts     = (int*)(hs + (size_t)N_NODES * 64);  // N
    int*   offsets    = counts + N_NODES;             // N
    int*   cursor     = offsets + N_NODES;            // N
    int*   sorted_src = cursor + N_NODES;             // E
    int*   bsum       = sorted_src + N_EDGES;         // SCAN_BLOCKS

    const int* srcI = ei;
    const int* dstI = ei + N_EDGES;

    hipMemsetAsync(counts, 0, N_NODES * sizeof(int), stream);
    hipLaunchKernelGGL(k_hist, dim3((N_EDGES + 255) / 256), dim3(256), 0, stream, dstI, counts);
    hipLaunchKernelGGL(k_scan1, dim3(SCAN_BLOCKS), dim3(256), 0, stream, counts, offsets, bsum);
    hipLaunchKernelGGL(k_scan2, dim3(1), dim3(128), 0, stream, bsum);
    hipLaunchKernelGGL(k_scan3, dim3(SCAN_BLOCKS), dim3(256), 0, stream, counts, offsets, cursor, dinv, bsum);
    hipLaunchKernelGGL(k_fill, dim3((N_EDGES + 255) / 256), dim3(256), 0, stream,
                       srcI, dstI, cursor, sorted_src);
    hipLaunchKernelGGL(k_gemm, dim3(N_NODES / 16), dim3(256), 0, stream, x, w, dinv, hs);
    hipLaunchKernelGGL(k_agg, dim3((N_NODES * 64) / 256), dim3(256), 0, stream,
                       offsets, counts, sorted_src, dinv, hs, bias, out);
}